// Round 13
// baseline (93.831 us; speedup 1.0000x reference)
//
#include <hip/hip_runtime.h>
#include <math.h>

#define B_ 4
#define L_ 1024
#define K_ 48
#define EF_ 128
#define NF_ 128
#define NPE_ 16
#define NRBF_ 16
#define MAXREL_ 32
#define EDGE_IN_ 416   // NPE + NRBF*25

#define V_SIZE   (B_*L_*NF_)          // 524288
#define E_OFF    (V_SIZE)
#define E_SIZE   (B_*L_*K_*EF_)       // 25165824
#define EIDX_OFF (E_OFF + E_SIZE)     // 25690112

#define XH_STRIDE 232                 // bf16 per half-row (224 + 8 pad), 464 B; 116 words -> 2-way banks

typedef __attribute__((ext_vector_type(8))) short bf16x8;
typedef __attribute__((ext_vector_type(4))) float f32x4;
typedef __attribute__((ext_vector_type(4))) unsigned u32x4;

// atom order: N=0, Ca=1, C=2, O=3, Cb=4. Group 0 = (Ca,Ca), then the 24 PAIRS.
__device__ const int PA_[25] = {1, 0,2,3,4, 1,1,1,1, 0,0,0, 4,4, 3, 0,2,3,4, 2,3,4, 2,3, 2};
__device__ const int PB_[25] = {1, 0,2,3,4, 0,2,3,4, 2,3,4, 2,3, 2, 1,1,1,1, 0,0,0, 4,4, 3};

__device__ __forceinline__ unsigned short f2bf(float f){   // RNE float->bf16
    unsigned u = __float_as_uint(f);
    unsigned r = u + 0x7fffu + ((u >> 16) & 1u);
    return (unsigned short)(r >> 16);
}

__device__ __forceinline__ float pair_dist(const float* sAI, const float (*sAJ)[16], int e, int g2) {
    float dx = sAI[PA_[g2]*3+0] - sAJ[e][PB_[g2]*3+0];
    float dy = sAI[PA_[g2]*3+1] - sAJ[e][PB_[g2]*3+1];
    float dz = sAI[PA_[g2]*3+2] - sAJ[e][PB_[g2]*3+2];
    return sqrtf(dx*dx + dy*dy + dz*dz + 1e-6f);
}

__device__ __forceinline__ void rbf16(unsigned short* dst, float dist) {
    float t = 0.8f * dist - 1.6f;
    unsigned pk[8];
    #pragma unroll
    for (int rr = 0; rr < 8; ++rr) {
        float v0 = __expf(-t * t); t -= 1.06666672f;
        float v1 = __expf(-t * t); t -= 1.06666672f;
        asm("v_cvt_pk_bf16_f32 %0, %1, %2" : "=v"(pk[rr]) : "v"(v0), "v"(v1));
    }
    u32x4 w0 = {pk[0], pk[1], pk[2], pk[3]};
    u32x4 w1 = {pk[4], pk[5], pk[6], pk[7]};
    *(u32x4*)dst = w0;
    *(u32x4*)(dst + 8) = w1;
}

template<int NKS, int KB>
__device__ __forceinline__ void mfma_half(f32x4 (&acc)[3][2], const unsigned short* xh,
                                          const unsigned short* w0p, const unsigned short* w1p,
                                          int lr, int lg) {
    #pragma unroll
    for (int ks = 0; ks < NKS; ++ks) {
        int k0 = ks * 32;
        bf16x8 a0, a1, a2, wb0, wb1;
        wb0 = *(const bf16x8*)(w0p + KB + k0);
        wb1 = *(const bf16x8*)(w1p + KB + k0);
        a0 = *(const bf16x8*)&xh[(lr)      * XH_STRIDE + k0 + lg*8];
        a1 = *(const bf16x8*)&xh[(16 + lr) * XH_STRIDE + k0 + lg*8];
        a2 = *(const bf16x8*)&xh[(32 + lr) * XH_STRIDE + k0 + lg*8];
        acc[0][0] = __builtin_amdgcn_mfma_f32_16x16x32_bf16(a0, wb0, acc[0][0], 0, 0, 0);
        acc[0][1] = __builtin_amdgcn_mfma_f32_16x16x32_bf16(a0, wb1, acc[0][1], 0, 0, 0);
        acc[1][0] = __builtin_amdgcn_mfma_f32_16x16x32_bf16(a1, wb0, acc[1][0], 0, 0, 0);
        acc[1][1] = __builtin_amdgcn_mfma_f32_16x16x32_bf16(a1, wb1, acc[1][1], 0, 0, 0);
        acc[2][0] = __builtin_amdgcn_mfma_f32_16x16x32_bf16(a2, wb0, acc[2][0], 0, 0, 0);
        acc[2][1] = __builtin_amdgcn_mfma_f32_16x16x32_bf16(a2, wb1, acc[2][1], 0, 0, 0);
    }
}

// ---------------- weight prep: fp32 [416][128] -> bf16 transposed [128][416] ----------------
__global__ __launch_bounds__(256) void wprep_kernel(const float* __restrict__ w,
                                                    unsigned short* __restrict__ wt)
{
    int idx = blockIdx.x * 256 + threadIdx.x;
    if (idx >= EDGE_IN_ * EF_) return;
    int f = idx & 127;
    int k = idx >> 7;
    wt[f * EDGE_IN_ + k] = f2bf(w[k * EF_ + f]);
}

// ---------------- V = LN(node_w[label]) ----------------
__global__ __launch_bounds__(128) void v_kernel(const int* __restrict__ labels,
                                                const float* __restrict__ node_w,
                                                const float* __restrict__ g,
                                                const float* __restrict__ bb,
                                                float* __restrict__ out)
{
    int gi = blockIdx.x;
    int f  = threadIdx.x;
    int lbl = labels[gi];
    float v = node_w[lbl*NF_ + f];

    __shared__ float red[2];
    __shared__ float red2[2];
    float s = v;
    #pragma unroll
    for (int m = 1; m < 64; m <<= 1) s += __shfl_xor(s, m, 64);
    if ((f & 63) == 0) red[f >> 6] = s;
    __syncthreads();
    float mu = (red[0] + red[1]) * (1.0f / NF_);
    float d = v - mu;
    float s2 = d * d;
    #pragma unroll
    for (int m = 1; m < 64; m <<= 1) s2 += __shfl_xor(s2, m, 64);
    if ((f & 63) == 0) red2[f >> 6] = s2;
    __syncthreads();
    float var = (red2[0] + red2[1]) * (1.0f / NF_);
    out[gi*NF_ + f] = d * rsqrtf(var + 1e-5f) * g[f] + bb[f];
}

// ---------------- fused: top-K select + edge features + MFMA + LN ----------------
// Phase 1: 4096-bin single-pass radix-select (exact; byte-radix fallback if bin>64).
// Phase 2: half-K staged features + MFMA; LN from accumulators via stats LDS.
// LDS alias plan (sBuf 22272 B):
//   phase1: sCa4[1024] float4 {x,y,z,mask} [0..16384) -> hist32[0..16384) cand@16384
//   phase2: xh[0..22272) -> (after last MFMA + barrier) stats@16384 stats2@17152
__global__ __launch_bounds__(256, 6) void fused_kernel(const float* __restrict__ X,
                                                   const float* __restrict__ mask,
                                                   const int* __restrict__ Ridx,
                                                   const int* __restrict__ chains,
                                                   const float* __restrict__ pe_w,
                                                   const float* __restrict__ pe_b,
                                                   const unsigned short* __restrict__ wt,
                                                   const float* __restrict__ ne_g,
                                                   const float* __restrict__ ne_b,
                                                   float* __restrict__ out)
{
    __shared__ __align__(16) unsigned char sBuf[K_ * XH_STRIDE * 2];
    __shared__ float sAI[16];
    __shared__ float sAJ[K_][16];
    __shared__ int   sJ[K_];
    __shared__ int   sDpos[K_];
    __shared__ float wmax[4];
    __shared__ unsigned wsum[4];
    __shared__ int sSelBin;
    __shared__ unsigned sSelLo, sSelCnt, sCnt, sCnt2;
    __shared__ unsigned long long sTkey;

    float* sCa4 = (float*)sBuf;                    // float4 per residue: {x,y,z,mask}
    unsigned* hist32 = (unsigned*)sBuf;
    unsigned short* xh = (unsigned short*)sBuf;
    unsigned long long* cand = (unsigned long long*)(sBuf + 16384);  // phase-1 tail
    float* stats  = (float*)(sBuf + 16384);                          // post-MFMA alias
    float* stats2 = (float*)(sBuf + 17152);

    int tid = threadIdx.x;
    int gi  = blockIdx.x;
    int b   = gi >> 10;
    int i   = gi & (L_ - 1);

    // ================= phase 1: top-K =================
    for (int j = tid; j < L_; j += 256) {
        const float* xr = X + ((size_t)((b << 10) + j)) * 12 + 3;   // Ca
        f32x4 c;
        c[0] = xr[0]; c[1] = xr[1]; c[2] = xr[2];
        c[3] = mask[(b << 10) + j];
        *(f32x4*)&sCa4[j*4] = c;
    }
    if (tid == 0) { sCnt = 0; sCnt2 = 0; }
    __syncthreads();

    f32x4 ci = *(f32x4*)&sCa4[i*4];
    float cx = ci[0], cy = ci[1], cz = ci[2], mi = ci[3];

    // one distance pass; dist/m2 stay in registers
    float dist4[4], m2r[4];
    float lmax = 0.0f;
    #pragma unroll
    for (int q = 0; q < 4; ++q) {
        int j = tid + q * 256;
        f32x4 cj = *(f32x4*)&sCa4[j*4];
        float dx = cx - cj[0];
        float dy = cy - cj[1];
        float dz = cz - cj[2];
        float dist = sqrtf(dx*dx + dy*dy + dz*dz + 1e-6f);
        float m2 = mi * cj[3];
        dist4[q] = dist; m2r[q] = m2;
        lmax = fmaxf(lmax, m2 * dist);
    }
    #pragma unroll
    for (int m = 1; m < 64; m <<= 1) lmax = fmaxf(lmax, __shfl_xor(lmax, m, 64));
    if ((tid & 63) == 0) wmax[tid >> 6] = lmax;
    __syncthreads();          // sCa4 dead after this point
    float Dmax = fmaxf(fmaxf(wmax[0], wmax[1]), fmaxf(wmax[2], wmax[3]));

    unsigned long long key[4];
    #pragma unroll
    for (int q = 0; q < 4; ++q) {
        int j = tid + q * 256;
        float Dadj = m2r[q] * dist4[q] + (1.0f - m2r[q]) * Dmax;
        key[q] = (((unsigned long long)__float_as_uint(Dadj)) << 32) | (unsigned)j;
    }

    // ---- 4096-bin histogram over Dadj bits [30:19] (key bits [62:51]) ----
    for (int k = tid; k < 4096; k += 256) hist32[k] = 0;
    __syncthreads();
    #pragma unroll
    for (int q = 0; q < 4; ++q)
        atomicAdd(&hist32[(unsigned)(key[q] >> 51) & 0xFFFu], 1u);
    __syncthreads();

    // scan: thread t owns bins [16t, 16t+16)
    u32x4 h4[4];
    #pragma unroll
    for (int k = 0; k < 4; ++k) h4[k] = *(u32x4*)&hist32[tid*16 + k*4];
    unsigned loc[16], tot = 0;
    #pragma unroll
    for (int k = 0; k < 16; ++k) { tot += h4[k>>2][k&3]; loc[k] = tot; }
    unsigned ws = tot;
    #pragma unroll
    for (int m = 1; m < 64; m <<= 1) {
        unsigned o = __shfl_up(ws, m, 64);
        if ((tid & 63) >= m) ws += o;
    }
    if ((tid & 63) == 63) wsum[tid >> 6] = ws;
    __syncthreads();
    unsigned base = ws - tot;
    for (int w = 0; w < (tid >> 6); ++w) base += wsum[w];
    unsigned lo_t = base;
    #pragma unroll
    for (int k = 0; k < 16; ++k) {
        unsigned hi_t = base + loc[k];
        if (47u >= lo_t && 47u < hi_t) { sSelBin = tid*16 + k; sSelLo = lo_t; sSelCnt = hi_t - lo_t; }
        lo_t = hi_t;
    }
    __syncthreads();
    unsigned bsel = (unsigned)sSelBin, lo = sSelLo, c = sSelCnt;
    unsigned long long T;

    if (c == 1) {
        #pragma unroll
        for (int q = 0; q < 4; ++q)
            if (((unsigned)(key[q] >> 51) & 0xFFFu) == bsel) sTkey = key[q];
        __syncthreads();
        T = sTkey;
    } else if (c <= 64) {
        #pragma unroll
        for (int q = 0; q < 4; ++q)
            if (((unsigned)(key[q] >> 51) & 0xFFFu) == bsel) {
                unsigned pos = atomicAdd(&sCnt, 1u);
                cand[pos] = key[q];
            }
        __syncthreads();
        if (tid < 64) {
            unsigned long long k64 = (tid < (int)c) ? cand[tid] : 0xffffffffffffffffULL;
            #pragma unroll
            for (unsigned kk = 2; kk <= 64; kk <<= 1) {
                #pragma unroll
                for (unsigned jj = kk >> 1; jj > 0; jj >>= 1) {
                    unsigned long long o = __shfl_xor(k64, jj, 64);
                    bool lower = (tid & jj) == 0;
                    bool asc   = (tid & kk) == 0;
                    unsigned long long mn = (k64 < o) ? k64 : o;
                    unsigned long long mx = (k64 < o) ? o : k64;
                    k64 = (lower == asc) ? mn : mx;
                }
            }
            if (tid == (int)(47u - lo)) sTkey = k64;   // exact rank-47 key
        }
        __syncthreads();
        T = sTkey;
    } else {
        // cold fallback: original exact 6-pass byte radix (256 bins reuse hist32)
        bool act[4] = {true, true, true, true};
        unsigned r = K_ - 1;
        T = 0;
        const int shifts[6] = {56, 48, 40, 32, 8, 0};
        #pragma unroll 1
        for (int p = 0; p < 6; ++p) {
            int sh = shifts[p];
            hist32[tid] = 0;
            __syncthreads();
            #pragma unroll
            for (int q = 0; q < 4; ++q)
                if (act[q]) atomicAdd(&hist32[(unsigned)((key[q] >> sh) & 255ULL)], 1u);
            __syncthreads();
            if (tid < 64) {
                unsigned b0 = hist32[tid*4+0], b1 = hist32[tid*4+1], b2 = hist32[tid*4+2], b3 = hist32[tid*4+3];
                unsigned s0 = b0, s1 = s0 + b1, s2 = s1 + b2, s3 = s2 + b3;
                unsigned s = s3;
                #pragma unroll
                for (int m = 1; m < 64; m <<= 1) {
                    unsigned o = __shfl_up(s, m, 64);
                    if (tid >= m) s += o;
                }
                unsigned bse = s - s3;
                hist32[tid*4+0] = bse + s0;
                hist32[tid*4+1] = bse + s1;
                hist32[tid*4+2] = bse + s2;
                hist32[tid*4+3] = bse + s3;
            }
            __syncthreads();
            unsigned lo2 = (tid == 0) ? 0u : hist32[tid - 1];
            unsigned hi2 = hist32[tid];
            if (r >= lo2 && r < hi2) { sSelBin = tid; sSelLo = lo2; }
            __syncthreads();
            int bs2 = sSelBin;
            r -= sSelLo;
            T |= ((unsigned long long)(unsigned)bs2) << sh;
            #pragma unroll
            for (int q = 0; q < 4; ++q)
                act[q] = act[q] && ((unsigned)((key[q] >> sh) & 255ULL) == (unsigned)bs2);
            __syncthreads();
        }
    }

    // exactly 48 keys <= T (keys unique); separate counter (no reset barrier)
    #pragma unroll
    for (int q = 0; q < 4; ++q)
        if (key[q] <= T) {
            unsigned pos = atomicAdd(&sCnt2, 1u);
            cand[pos] = key[q];
        }
    __syncthreads();

    // wave 0: in-register bitonic sort of 64 (48 real + pad), emit ascending
    if (tid < 64) {
        unsigned long long k64 = (tid < K_) ? cand[tid] : 0xffffffffffffffffULL;
        #pragma unroll
        for (unsigned kk = 2; kk <= 64; kk <<= 1) {
            #pragma unroll
            for (unsigned jj = kk >> 1; jj > 0; jj >>= 1) {
                unsigned long long o = __shfl_xor(k64, jj, 64);
                bool lower = (tid & jj) == 0;
                bool asc   = (tid & kk) == 0;
                unsigned long long mn = (k64 < o) ? k64 : o;
                unsigned long long mx = (k64 < o) ? o : k64;
                k64 = (lower == asc) ? mn : mx;
            }
        }
        if (tid < K_) {
            int j = (int)(unsigned)(k64 & 0xffffffffULL);
            sJ[tid] = j;
            out[EIDX_OFF + (size_t)gi * K_ + tid] = (float)j;
        }
    }
    __syncthreads();

    // ================= phase 2: edge features + MFMA + LN =================
    if (tid < K_ + 1) {
        int rr = (tid < K_) ? sJ[tid] : i;
        const float* xr = X + ((size_t)((b << 10) + rr)) * 12;
        float n0=xr[0],  n1=xr[1],  n2=xr[2];
        float a0=xr[3],  a1=xr[4],  a2=xr[5];
        float c0=xr[6],  c1=xr[7],  c2=xr[8];
        float o0=xr[9],  o1=xr[10], o2=xr[11];
        float bx=a0-n0, by=a1-n1, bz=a2-n2;
        float vx=c0-a0, vy=c1-a1, vz=c2-a2;
        float ax = by*vz - bz*vy;
        float ay = bz*vx - bx*vz;
        float az = bx*vy - by*vx;
        float cb0 = -0.58273431f*ax + 0.56802827f*bx - 0.54067466f*vx + a0;
        float cb1 = -0.58273431f*ay + 0.56802827f*by - 0.54067466f*vy + a1;
        float cb2 = -0.58273431f*az + 0.56802827f*bz - 0.54067466f*vz + a2;
        float* dst = (tid < K_) ? &sAJ[tid][0] : &sAI[0];
        dst[0]=n0;  dst[1]=n1;  dst[2]=n2;
        dst[3]=a0;  dst[4]=a1;  dst[5]=a2;
        dst[6]=c0;  dst[7]=c1;  dst[8]=c2;
        dst[9]=o0;  dst[10]=o1; dst[11]=o2;
        dst[12]=cb0; dst[13]=cb1; dst[14]=cb2;
    }
    if (tid >= 64 && tid < 64 + K_) {
        int e = tid - 64;
        int j = sJ[e];
        int off  = Ridx[gi] - Ridx[(b << 10) + j];
        int same = (chains[gi] == chains[(b << 10) + j]);
        int dcl = off + MAXREL_;
        dcl = dcl < 0 ? 0 : (dcl > 2*MAXREL_ ? 2*MAXREL_ : dcl);
        sDpos[e] = same ? dcl : (2*MAXREL_ + 1);
    }
    __syncthreads();

    const int wv = tid >> 6;
    const int ln = tid & 63;
    const int lr = ln & 15;
    const int lg = ln >> 4;

    f32x4 acc[3][2];
    #pragma unroll
    for (int rf = 0; rf < 3; ++rf)
        #pragma unroll
        for (int cf = 0; cf < 2; ++cf)
            acc[rf][cf] = (f32x4){0.0f, 0.0f, 0.0f, 0.0f};

    const unsigned short* wbase0 = wt + (size_t)(wv*32 + lr) * EDGE_IN_ + lg*8;
    const unsigned short* wbase1 = wt + (size_t)(wv*32 + 16 + lr) * EDGE_IN_ + lg*8;

    // half 0: PE (cols 0..15) + groups 0..12 (cols 16..223); K 0..223
    // fill mapping e = idx%48 (consecutive lanes -> consecutive e -> 2-way banks)
    #pragma unroll
    for (int p = 0; p < 2; ++p) {
        int idx = tid + p * 256;
        if (idx < 384) {
            int e = idx >> 3, cc = (idx & 7) * 2;
            int dp = sDpos[e];
            float v0 = pe_w[dp*NPE_ + cc]     + pe_b[cc];
            float v1 = pe_w[dp*NPE_ + cc + 1] + pe_b[cc + 1];
            unsigned pk;
            asm("v_cvt_pk_bf16_f32 %0, %1, %2" : "=v"(pk) : "v"(v0), "v"(v1));
            *(unsigned*)&xh[e * XH_STRIDE + cc] = pk;
        }
    }
    #pragma unroll
    for (int p = 0; p < 3; ++p) {       // 13 groups x 48 edges = 624 items
        int idx = tid + p * 256;
        if (idx < 624) {
            int g = idx / 48, e = idx - g * 48;
            rbf16(&xh[e * XH_STRIDE + NPE_ + g * 16], pair_dist(sAI, sAJ, e, g));
        }
    }
    __syncthreads();
    mfma_half<7, 0>(acc, xh, wbase0, wbase1, lr, lg);
    __syncthreads();
    // half 1: groups 13..24 (cols 0..191 local); K 224..415
    #pragma unroll
    for (int p = 0; p < 3; ++p) {       // 12 groups x 48 edges = 576 items
        int idx = tid + p * 256;
        if (idx < 576) {
            int g = idx / 48, e = idx - g * 48;
            rbf16(&xh[e * XH_STRIDE + g * 16], pair_dist(sAI, sAJ, e, 13 + g));
        }
    }
    __syncthreads();
    mfma_half<6, 224>(acc, xh, wbase0, wbase1, lr, lg);
    __syncthreads();   // xh reads complete before stats alias is written

    // ---- LN from accumulators: per-row stats via lr-group shfl + stats LDS ----
    #pragma unroll
    for (int rf = 0; rf < 3; ++rf)
        #pragma unroll
        for (int r4 = 0; r4 < 4; ++r4) {
            float v0 = acc[rf][0][r4], v1 = acc[rf][1][r4];
            float s  = v0 + v1;
            float s2 = v0*v0 + v1*v1;
            #pragma unroll
            for (int m = 1; m < 16; m <<= 1) {
                s  += __shfl_xor(s,  m, 64);
                s2 += __shfl_xor(s2, m, 64);
            }
            if (lr == 0) {
                int row = rf*16 + lg*4 + r4;
                stats [wv*K_ + row] = s;
                stats2[wv*K_ + row] = s2;
            }
        }
    __syncthreads();

    int colg = wv*32 + lr;
    float gv0 = ne_g[colg],      bv0 = ne_b[colg];
    float gv1 = ne_g[colg + 16], bv1 = ne_b[colg + 16];

    #pragma unroll
    for (int rf = 0; rf < 3; ++rf)
        #pragma unroll
        for (int r4 = 0; r4 < 4; ++r4) {
            int row = rf*16 + lg*4 + r4;
            float sum = stats [row] + stats [K_ + row] + stats [2*K_ + row] + stats [3*K_ + row];
            float sq  = stats2[row] + stats2[K_ + row] + stats2[2*K_ + row] + stats2[3*K_ + row];
            float mu   = sum * (1.0f / 128.0f);
            float var  = sq * (1.0f / 128.0f) - mu * mu;
            float rstd = rsqrtf(var + 1e-5f);
            float* dst = out + E_OFF + (size_t)(gi * K_ + row) * EF_ + colg;
            __builtin_nontemporal_store((acc[rf][0][r4] - mu) * rstd * gv0 + bv0, dst);
            __builtin_nontemporal_store((acc[rf][1][r4] - mu) * rstd * gv1 + bv1, dst + 16);
        }
}

extern "C" void kernel_launch(void* const* d_in, const int* in_sizes, int n_in,
                              void* d_out, int out_size, void* d_ws, size_t ws_size,
                              hipStream_t stream)
{
    const float* X      = (const float*)d_in[0];
    const float* mask   = (const float*)d_in[1];
    const int*   Ridx   = (const int*)d_in[2];
    const int*   chains = (const int*)d_in[3];
    const int*   memb   = (const int*)d_in[4];
    const float* pe_w   = (const float*)d_in[5];
    const float* pe_b   = (const float*)d_in[6];
    const float* edge_w = (const float*)d_in[7];
    const float* ne_g   = (const float*)d_in[8];
    const float* ne_b   = (const float*)d_in[9];
    const float* node_w = (const float*)d_in[10];
    const float* nn_g   = (const float*)d_in[11];
    const float* nn_b   = (const float*)d_in[12];
    float* out = (float*)d_out;

    unsigned short* wt = (unsigned short*)d_ws;

    wprep_kernel<<<(EDGE_IN_*EF_ + 255)/256, 256, 0, stream>>>(edge_w, wt);
    v_kernel<<<B_*L_, 128, 0, stream>>>(memb, node_w, nn_g, nn_b, out);
    fused_kernel<<<B_*L_, 256, 0, stream>>>(X, mask, Ridx, chains, pe_w, pe_b,
                                            wt, ne_g, ne_b, out);
}

// Round 14
// 91.047 us; speedup vs baseline: 1.0306x; 1.0306x over previous
//
#include <hip/hip_runtime.h>
#include <math.h>

#define B_ 4
#define L_ 1024
#define K_ 48
#define EF_ 128
#define NF_ 128
#define NPE_ 16
#define NRBF_ 16
#define MAXREL_ 32
#define EDGE_IN_ 416   // NPE + NRBF*25

#define V_SIZE   (B_*L_*NF_)          // 524288
#define E_OFF    (V_SIZE)
#define E_SIZE   (B_*L_*K_*EF_)       // 25165824
#define EIDX_OFF (E_OFF + E_SIZE)     // 25690112

#define XH_STRIDE 232                 // bf16 per half-row (224 + 8 pad), 464 B

typedef __attribute__((ext_vector_type(8))) short bf16x8;
typedef __attribute__((ext_vector_type(4))) float f32x4;
typedef __attribute__((ext_vector_type(4))) unsigned u32x4;

// atom order: N=0, Ca=1, C=2, O=3, Cb=4. Group 0 = (Ca,Ca), then the 24 PAIRS.
__device__ const int PA_[25] = {1, 0,2,3,4, 1,1,1,1, 0,0,0, 4,4, 3, 0,2,3,4, 2,3,4, 2,3, 2};
__device__ const int PB_[25] = {1, 0,2,3,4, 0,2,3,4, 2,3,4, 2,3, 2, 1,1,1,1, 0,0,0, 4,4, 3};

__device__ __forceinline__ unsigned short f2bf(float f){   // RNE float->bf16
    unsigned u = __float_as_uint(f);
    unsigned r = u + 0x7fffu + ((u >> 16) & 1u);
    return (unsigned short)(r >> 16);
}

__device__ __forceinline__ float pair_dist(const float* sAI, const float (*sAJ)[16], int e, int g2) {
    float dx = sAI[PA_[g2]*3+0] - sAJ[e][PB_[g2]*3+0];
    float dy = sAI[PA_[g2]*3+1] - sAJ[e][PB_[g2]*3+1];
    float dz = sAI[PA_[g2]*3+2] - sAJ[e][PB_[g2]*3+2];
    return sqrtf(dx*dx + dy*dy + dz*dz + 1e-6f);
}

__device__ __forceinline__ void rbf_regs(unsigned* pk, float dist) {
    float t = 0.8f * dist - 1.6f;
    #pragma unroll
    for (int rr = 0; rr < 8; ++rr) {
        float v0 = __expf(-t * t); t -= 1.06666672f;
        float v1 = __expf(-t * t); t -= 1.06666672f;
        asm("v_cvt_pk_bf16_f32 %0, %1, %2" : "=v"(pk[rr]) : "v"(v0), "v"(v1));
    }
}

__device__ __forceinline__ void rbf16(unsigned short* dst, float dist) {
    unsigned pk[8];
    rbf_regs(pk, dist);
    u32x4 w0 = {pk[0], pk[1], pk[2], pk[3]};
    u32x4 w1 = {pk[4], pk[5], pk[6], pk[7]};
    *(u32x4*)dst = w0;
    *(u32x4*)(dst + 8) = w1;
}

template<int FROM, int TO, int KB>
__device__ __forceinline__ void mfma_steps(f32x4 (&acc)[3][2], const unsigned short* xh,
                                           const unsigned short* w0p, const unsigned short* w1p,
                                           int lr, int lg) {
    #pragma unroll
    for (int ks = FROM; ks < TO; ++ks) {
        int k0 = ks * 32;
        bf16x8 a0, a1, a2, wb0, wb1;
        wb0 = *(const bf16x8*)(w0p + KB + k0);
        wb1 = *(const bf16x8*)(w1p + KB + k0);
        a0 = *(const bf16x8*)&xh[(lr)      * XH_STRIDE + k0 + lg*8];
        a1 = *(const bf16x8*)&xh[(16 + lr) * XH_STRIDE + k0 + lg*8];
        a2 = *(const bf16x8*)&xh[(32 + lr) * XH_STRIDE + k0 + lg*8];
        acc[0][0] = __builtin_amdgcn_mfma_f32_16x16x32_bf16(a0, wb0, acc[0][0], 0, 0, 0);
        acc[0][1] = __builtin_amdgcn_mfma_f32_16x16x32_bf16(a0, wb1, acc[0][1], 0, 0, 0);
        acc[1][0] = __builtin_amdgcn_mfma_f32_16x16x32_bf16(a1, wb0, acc[1][0], 0, 0, 0);
        acc[1][1] = __builtin_amdgcn_mfma_f32_16x16x32_bf16(a1, wb1, acc[1][1], 0, 0, 0);
        acc[2][0] = __builtin_amdgcn_mfma_f32_16x16x32_bf16(a2, wb0, acc[2][0], 0, 0, 0);
        acc[2][1] = __builtin_amdgcn_mfma_f32_16x16x32_bf16(a2, wb1, acc[2][1], 0, 0, 0);
    }
}

// ---------------- weight prep: fp32 [416][128] -> bf16 transposed [128][416] ----------------
__global__ __launch_bounds__(256) void wprep_kernel(const float* __restrict__ w,
                                                    unsigned short* __restrict__ wt)
{
    int idx = blockIdx.x * 256 + threadIdx.x;
    if (idx >= EDGE_IN_ * EF_) return;
    int f = idx & 127;
    int k = idx >> 7;
    wt[f * EDGE_IN_ + k] = f2bf(w[k * EF_ + f]);
}

// ---------------- V = LN(node_w[label]) ----------------
__global__ __launch_bounds__(128) void v_kernel(const int* __restrict__ labels,
                                                const float* __restrict__ node_w,
                                                const float* __restrict__ g,
                                                const float* __restrict__ bb,
                                                float* __restrict__ out)
{
    int gi = blockIdx.x;
    int f  = threadIdx.x;
    int lbl = labels[gi];
    float v = node_w[lbl*NF_ + f];

    __shared__ float red[2];
    __shared__ float red2[2];
    float s = v;
    #pragma unroll
    for (int m = 1; m < 64; m <<= 1) s += __shfl_xor(s, m, 64);
    if ((f & 63) == 0) red[f >> 6] = s;
    __syncthreads();
    float mu = (red[0] + red[1]) * (1.0f / NF_);
    float d = v - mu;
    float s2 = d * d;
    #pragma unroll
    for (int m = 1; m < 64; m <<= 1) s2 += __shfl_xor(s2, m, 64);
    if ((f & 63) == 0) red2[f >> 6] = s2;
    __syncthreads();
    float var = (red2[0] + red2[1]) * (1.0f / NF_);
    out[gi*NF_ + f] = d * rsqrtf(var + 1e-5f) * g[f] + bb[f];
}

// ---------------- fused: top-K select + edge features + MFMA + LN ----------------
// Phase 1: 4096-bin single-pass radix-select (exact; byte-radix fallback if bin>64).
// Phase 2: half-K staged features + MFMA; half-1 RBF computed into REGISTERS during
// half-0's MFMA phase (separate pipes), stored to LDS after the existing barrier.
// LDS alias plan (sBuf 22272 B):
//   phase1: sCa[0..12288) sM[12288..16384) -> hist32[0..16384) cand@16384
//   phase2: xh[0..22272) -> (after last MFMA + barrier) stats@16384 stats2@17152
__global__ __launch_bounds__(256, 6) void fused_kernel(const float* __restrict__ X,
                                                   const float* __restrict__ mask,
                                                   const int* __restrict__ Ridx,
                                                   const int* __restrict__ chains,
                                                   const float* __restrict__ pe_w,
                                                   const float* __restrict__ pe_b,
                                                   const unsigned short* __restrict__ wt,
                                                   const float* __restrict__ ne_g,
                                                   const float* __restrict__ ne_b,
                                                   float* __restrict__ out)
{
    __shared__ __align__(16) unsigned char sBuf[K_ * XH_STRIDE * 2];
    __shared__ float sAI[16];
    __shared__ float sAJ[K_][16];
    __shared__ int   sJ[K_];
    __shared__ int   sDpos[K_];
    __shared__ float wmax[4];
    __shared__ unsigned wsum[4];
    __shared__ int sSelBin;
    __shared__ unsigned sSelLo, sSelCnt, sCnt, sCnt2;
    __shared__ unsigned long long sTkey;

    float* sCa = (float*)sBuf;
    float* sM  = (float*)(sBuf + 12288);
    unsigned* hist32 = (unsigned*)sBuf;
    unsigned short* xh = (unsigned short*)sBuf;
    unsigned long long* cand = (unsigned long long*)(sBuf + 16384);  // phase-1 tail
    float* stats  = (float*)(sBuf + 16384);                          // post-MFMA alias
    float* stats2 = (float*)(sBuf + 17152);

    int tid = threadIdx.x;
    int gi  = blockIdx.x;
    int b   = gi >> 10;
    int i   = gi & (L_ - 1);

    // ================= phase 1: top-K =================
    for (int j = tid; j < L_; j += 256) {
        const float* xr = X + ((size_t)((b << 10) + j)) * 12 + 3;   // Ca
        sCa[j*3+0] = xr[0];
        sCa[j*3+1] = xr[1];
        sCa[j*3+2] = xr[2];
        sM[j] = mask[(b << 10) + j];
    }
    if (tid == 0) { sCnt = 0; sCnt2 = 0; }
    __syncthreads();

    float cx = sCa[i*3+0], cy = sCa[i*3+1], cz = sCa[i*3+2];
    float mi = sM[i];

    // one distance pass; dist/m2 stay in registers
    float dist4[4], m2r[4];
    float lmax = 0.0f;
    #pragma unroll
    for (int q = 0; q < 4; ++q) {
        int j = tid + q * 256;
        float dx = cx - sCa[j*3+0];
        float dy = cy - sCa[j*3+1];
        float dz = cz - sCa[j*3+2];
        float dist = sqrtf(dx*dx + dy*dy + dz*dz + 1e-6f);
        float m2 = mi * sM[j];
        dist4[q] = dist; m2r[q] = m2;
        lmax = fmaxf(lmax, m2 * dist);
    }
    #pragma unroll
    for (int m = 1; m < 64; m <<= 1) lmax = fmaxf(lmax, __shfl_xor(lmax, m, 64));
    if ((tid & 63) == 0) wmax[tid >> 6] = lmax;
    __syncthreads();          // sCa/sM dead after this point
    float Dmax = fmaxf(fmaxf(wmax[0], wmax[1]), fmaxf(wmax[2], wmax[3]));

    unsigned long long key[4];
    #pragma unroll
    for (int q = 0; q < 4; ++q) {
        int j = tid + q * 256;
        float Dadj = m2r[q] * dist4[q] + (1.0f - m2r[q]) * Dmax;
        key[q] = (((unsigned long long)__float_as_uint(Dadj)) << 32) | (unsigned)j;
    }

    // ---- 4096-bin histogram over Dadj bits [30:19] (key bits [62:51]) ----
    for (int k = tid; k < 4096; k += 256) hist32[k] = 0;
    __syncthreads();
    #pragma unroll
    for (int q = 0; q < 4; ++q)
        atomicAdd(&hist32[(unsigned)(key[q] >> 51) & 0xFFFu], 1u);
    __syncthreads();

    // scan: thread t owns bins [16t, 16t+16)
    u32x4 h4[4];
    #pragma unroll
    for (int k = 0; k < 4; ++k) h4[k] = *(u32x4*)&hist32[tid*16 + k*4];
    unsigned loc[16], tot = 0;
    #pragma unroll
    for (int k = 0; k < 16; ++k) { tot += h4[k>>2][k&3]; loc[k] = tot; }
    unsigned ws = tot;
    #pragma unroll
    for (int m = 1; m < 64; m <<= 1) {
        unsigned o = __shfl_up(ws, m, 64);
        if ((tid & 63) >= m) ws += o;
    }
    if ((tid & 63) == 63) wsum[tid >> 6] = ws;
    __syncthreads();
    unsigned base = ws - tot;
    for (int w = 0; w < (tid >> 6); ++w) base += wsum[w];
    unsigned lo_t = base;
    #pragma unroll
    for (int k = 0; k < 16; ++k) {
        unsigned hi_t = base + loc[k];
        if (47u >= lo_t && 47u < hi_t) { sSelBin = tid*16 + k; sSelLo = lo_t; sSelCnt = hi_t - lo_t; }
        lo_t = hi_t;
    }
    __syncthreads();
    unsigned bsel = (unsigned)sSelBin, lo = sSelLo, c = sSelCnt;
    unsigned long long T;

    if (c == 1) {
        #pragma unroll
        for (int q = 0; q < 4; ++q)
            if (((unsigned)(key[q] >> 51) & 0xFFFu) == bsel) sTkey = key[q];
        __syncthreads();
        T = sTkey;
    } else if (c <= 64) {
        #pragma unroll
        for (int q = 0; q < 4; ++q)
            if (((unsigned)(key[q] >> 51) & 0xFFFu) == bsel) {
                unsigned pos = atomicAdd(&sCnt, 1u);
                cand[pos] = key[q];
            }
        __syncthreads();
        if (tid < 64) {
            unsigned long long k64 = (tid < (int)c) ? cand[tid] : 0xffffffffffffffffULL;
            #pragma unroll
            for (unsigned kk = 2; kk <= 64; kk <<= 1) {
                #pragma unroll
                for (unsigned jj = kk >> 1; jj > 0; jj >>= 1) {
                    unsigned long long o = __shfl_xor(k64, jj, 64);
                    bool lower = (tid & jj) == 0;
                    bool asc   = (tid & kk) == 0;
                    unsigned long long mn = (k64 < o) ? k64 : o;
                    unsigned long long mx = (k64 < o) ? o : k64;
                    k64 = (lower == asc) ? mn : mx;
                }
            }
            if (tid == (int)(47u - lo)) sTkey = k64;   // exact rank-47 key
        }
        __syncthreads();
        T = sTkey;
    } else {
        // cold fallback: original exact 6-pass byte radix (256 bins reuse hist32)
        bool act[4] = {true, true, true, true};
        unsigned r = K_ - 1;
        T = 0;
        const int shifts[6] = {56, 48, 40, 32, 8, 0};
        #pragma unroll 1
        for (int p = 0; p < 6; ++p) {
            int sh = shifts[p];
            hist32[tid] = 0;
            __syncthreads();
            #pragma unroll
            for (int q = 0; q < 4; ++q)
                if (act[q]) atomicAdd(&hist32[(unsigned)((key[q] >> sh) & 255ULL)], 1u);
            __syncthreads();
            if (tid < 64) {
                unsigned b0 = hist32[tid*4+0], b1 = hist32[tid*4+1], b2 = hist32[tid*4+2], b3 = hist32[tid*4+3];
                unsigned s0 = b0, s1 = s0 + b1, s2 = s1 + b2, s3 = s2 + b3;
                unsigned s = s3;
                #pragma unroll
                for (int m = 1; m < 64; m <<= 1) {
                    unsigned o = __shfl_up(s, m, 64);
                    if (tid >= m) s += o;
                }
                unsigned bse = s - s3;
                hist32[tid*4+0] = bse + s0;
                hist32[tid*4+1] = bse + s1;
                hist32[tid*4+2] = bse + s2;
                hist32[tid*4+3] = bse + s3;
            }
            __syncthreads();
            unsigned lo2 = (tid == 0) ? 0u : hist32[tid - 1];
            unsigned hi2 = hist32[tid];
            if (r >= lo2 && r < hi2) { sSelBin = tid; sSelLo = lo2; }
            __syncthreads();
            int bs2 = sSelBin;
            r -= sSelLo;
            T |= ((unsigned long long)(unsigned)bs2) << sh;
            #pragma unroll
            for (int q = 0; q < 4; ++q)
                act[q] = act[q] && ((unsigned)((key[q] >> sh) & 255ULL) == (unsigned)bs2);
            __syncthreads();
        }
    }

    // exactly 48 keys <= T (keys unique); separate counter (no reset barrier)
    #pragma unroll
    for (int q = 0; q < 4; ++q)
        if (key[q] <= T) {
            unsigned pos = atomicAdd(&sCnt2, 1u);
            cand[pos] = key[q];
        }
    __syncthreads();

    // wave 0: in-register bitonic sort of 64 (48 real + pad), emit ascending
    if (tid < 64) {
        unsigned long long k64 = (tid < K_) ? cand[tid] : 0xffffffffffffffffULL;
        #pragma unroll
        for (unsigned kk = 2; kk <= 64; kk <<= 1) {
            #pragma unroll
            for (unsigned jj = kk >> 1; jj > 0; jj >>= 1) {
                unsigned long long o = __shfl_xor(k64, jj, 64);
                bool lower = (tid & jj) == 0;
                bool asc   = (tid & kk) == 0;
                unsigned long long mn = (k64 < o) ? k64 : o;
                unsigned long long mx = (k64 < o) ? o : k64;
                k64 = (lower == asc) ? mn : mx;
            }
        }
        if (tid < K_) {
            int j = (int)(unsigned)(k64 & 0xffffffffULL);
            sJ[tid] = j;
            out[EIDX_OFF + (size_t)gi * K_ + tid] = (float)j;
        }
    }
    __syncthreads();

    // ================= phase 2: edge features + MFMA + LN =================
    if (tid < K_ + 1) {
        int rr = (tid < K_) ? sJ[tid] : i;
        const float* xr = X + ((size_t)((b << 10) + rr)) * 12;
        float n0=xr[0],  n1=xr[1],  n2=xr[2];
        float a0=xr[3],  a1=xr[4],  a2=xr[5];
        float c0=xr[6],  c1=xr[7],  c2=xr[8];
        float o0=xr[9],  o1=xr[10], o2=xr[11];
        float bx=a0-n0, by=a1-n1, bz=a2-n2;
        float vx=c0-a0, vy=c1-a1, vz=c2-a2;
        float ax = by*vz - bz*vy;
        float ay = bz*vx - bx*vz;
        float az = bx*vy - by*vx;
        float cb0 = -0.58273431f*ax + 0.56802827f*bx - 0.54067466f*vx + a0;
        float cb1 = -0.58273431f*ay + 0.56802827f*by - 0.54067466f*vy + a1;
        float cb2 = -0.58273431f*az + 0.56802827f*bz - 0.54067466f*vz + a2;
        float* dst = (tid < K_) ? &sAJ[tid][0] : &sAI[0];
        dst[0]=n0;  dst[1]=n1;  dst[2]=n2;
        dst[3]=a0;  dst[4]=a1;  dst[5]=a2;
        dst[6]=c0;  dst[7]=c1;  dst[8]=c2;
        dst[9]=o0;  dst[10]=o1; dst[11]=o2;
        dst[12]=cb0; dst[13]=cb1; dst[14]=cb2;
    }
    if (tid >= 64 && tid < 64 + K_) {
        int e = tid - 64;
        int j = sJ[e];
        int off  = Ridx[gi] - Ridx[(b << 10) + j];
        int same = (chains[gi] == chains[(b << 10) + j]);
        int dcl = off + MAXREL_;
        dcl = dcl < 0 ? 0 : (dcl > 2*MAXREL_ ? 2*MAXREL_ : dcl);
        sDpos[e] = same ? dcl : (2*MAXREL_ + 1);
    }
    __syncthreads();

    const int wv = tid >> 6;
    const int ln = tid & 63;
    const int lr = ln & 15;
    const int lg = ln >> 4;

    f32x4 acc[3][2];
    #pragma unroll
    for (int rf = 0; rf < 3; ++rf)
        #pragma unroll
        for (int cf = 0; cf < 2; ++cf)
            acc[rf][cf] = (f32x4){0.0f, 0.0f, 0.0f, 0.0f};

    const unsigned short* wbase0 = wt + (size_t)(wv*32 + lr) * EDGE_IN_ + lg*8;
    const unsigned short* wbase1 = wt + (size_t)(wv*32 + 16 + lr) * EDGE_IN_ + lg*8;

    // half 0: PE (cols 0..15) + groups 0..12 (cols 16..223); K 0..223 (R12 mapping)
    #pragma unroll
    for (int p = 0; p < 2; ++p) {
        int idx = tid + p * 256;
        if (idx < 384) {
            int e = idx >> 3, cc = (idx & 7) * 2;
            int dp = sDpos[e];
            float v0 = pe_w[dp*NPE_ + cc]     + pe_b[cc];
            float v1 = pe_w[dp*NPE_ + cc + 1] + pe_b[cc + 1];
            unsigned pk;
            asm("v_cvt_pk_bf16_f32 %0, %1, %2" : "=v"(pk) : "v"(v0), "v"(v1));
            *(unsigned*)&xh[e * XH_STRIDE + cc] = pk;
        }
    }
    #pragma unroll
    for (int p = 0; p < 3; ++p) {       // 48 x 13 groups = 624 items
        int idx = tid + p * 256;
        if (idx < 624) {
            int e = idx / 13, g = idx - e * 13;
            rbf16(&xh[e * XH_STRIDE + NPE_ + g * 16], pair_dist(sAI, sAJ, e, g));
        }
    }
    __syncthreads();

    // ---- half-0 MFMA interleaved with half-1 RBF computed into registers ----
    // half-1 items: 576 = p0 (all), p1 (all), p2 (tid<64). R12 mapping e=idx/12.
    unsigned pkr0[8], pkr1[8], pkr2[8];

    mfma_steps<0, 2, 0>(acc, xh, wbase0, wbase1, lr, lg);
    {
        int idx = tid;
        int e = idx / 12, gg = idx - e * 12;
        rbf_regs(pkr0, pair_dist(sAI, sAJ, e, 13 + gg));
    }
    mfma_steps<2, 4, 0>(acc, xh, wbase0, wbase1, lr, lg);
    {
        int idx = tid + 256;
        int e = idx / 12, gg = idx - e * 12;
        rbf_regs(pkr1, pair_dist(sAI, sAJ, e, 13 + gg));
    }
    mfma_steps<4, 6, 0>(acc, xh, wbase0, wbase1, lr, lg);
    if (tid < 64) {
        int idx = tid + 512;
        int e = idx / 12, gg = idx - e * 12;
        rbf_regs(pkr2, pair_dist(sAI, sAJ, e, 13 + gg));
    }
    mfma_steps<6, 7, 0>(acc, xh, wbase0, wbase1, lr, lg);
    __syncthreads();   // all xh half-0 reads complete

    // store half-1 registers to xh (cols 0..191 local = global 224..415)
    {
        int e0 = tid / 12,        gg0 = tid - e0 * 12;
        u32x4 w0 = {pkr0[0], pkr0[1], pkr0[2], pkr0[3]};
        u32x4 w1 = {pkr0[4], pkr0[5], pkr0[6], pkr0[7]};
        *(u32x4*)&xh[e0 * XH_STRIDE + gg0 * 16]     = w0;
        *(u32x4*)&xh[e0 * XH_STRIDE + gg0 * 16 + 8] = w1;

        int i1 = tid + 256;
        int e1 = i1 / 12,         gg1 = i1 - e1 * 12;
        u32x4 w2 = {pkr1[0], pkr1[1], pkr1[2], pkr1[3]};
        u32x4 w3 = {pkr1[4], pkr1[5], pkr1[6], pkr1[7]};
        *(u32x4*)&xh[e1 * XH_STRIDE + gg1 * 16]     = w2;
        *(u32x4*)&xh[e1 * XH_STRIDE + gg1 * 16 + 8] = w3;

        if (tid < 64) {
            int i2 = tid + 512;
            int e2 = i2 / 12,     gg2 = i2 - e2 * 12;
            u32x4 w4 = {pkr2[0], pkr2[1], pkr2[2], pkr2[3]};
            u32x4 w5 = {pkr2[4], pkr2[5], pkr2[6], pkr2[7]};
            *(u32x4*)&xh[e2 * XH_STRIDE + gg2 * 16]     = w4;
            *(u32x4*)&xh[e2 * XH_STRIDE + gg2 * 16 + 8] = w5;
        }
    }
    __syncthreads();
    mfma_steps<0, 6, 224>(acc, xh, wbase0, wbase1, lr, lg);
    __syncthreads();   // xh reads complete before stats alias is written

    // ---- LN from accumulators: per-row stats via lr-group shfl + stats LDS ----
    #pragma unroll
    for (int rf = 0; rf < 3; ++rf)
        #pragma unroll
        for (int r4 = 0; r4 < 4; ++r4) {
            float v0 = acc[rf][0][r4], v1 = acc[rf][1][r4];
            float s  = v0 + v1;
            float s2 = v0*v0 + v1*v1;
            #pragma unroll
            for (int m = 1; m < 16; m <<= 1) {
                s  += __shfl_xor(s,  m, 64);
                s2 += __shfl_xor(s2, m, 64);
            }
            if (lr == 0) {
                int row = rf*16 + lg*4 + r4;
                stats [wv*K_ + row] = s;
                stats2[wv*K_ + row] = s2;
            }
        }
    __syncthreads();

    int colg = wv*32 + lr;
    float gv0 = ne_g[colg],      bv0 = ne_b[colg];
    float gv1 = ne_g[colg + 16], bv1 = ne_b[colg + 16];

    #pragma unroll
    for (int rf = 0; rf < 3; ++rf)
        #pragma unroll
        for (int r4 = 0; r4 < 4; ++r4) {
            int row = rf*16 + lg*4 + r4;
            float sum = stats [row] + stats [K_ + row] + stats [2*K_ + row] + stats [3*K_ + row];
            float sq  = stats2[row] + stats2[K_ + row] + stats2[2*K_ + row] + stats2[3*K_ + row];
            float mu   = sum * (1.0f / 128.0f);
            float var  = sq * (1.0f / 128.0f) - mu * mu;
            float rstd = rsqrtf(var + 1e-5f);
            float* dst = out + E_OFF + (size_t)(gi * K_ + row) * EF_ + colg;
            __builtin_nontemporal_store((acc[rf][0][r4] - mu) * rstd * gv0 + bv0, dst);
            __builtin_nontemporal_store((acc[rf][1][r4] - mu) * rstd * gv1 + bv1, dst + 16);
        }
}

extern "C" void kernel_launch(void* const* d_in, const int* in_sizes, int n_in,
                              void* d_out, int out_size, void* d_ws, size_t ws_size,
                              hipStream_t stream)
{
    const float* X      = (const float*)d_in[0];
    const float* mask   = (const float*)d_in[1];
    const int*   Ridx   = (const int*)d_in[2];
    const int*   chains = (const int*)d_in[3];
    const int*   memb   = (const int*)d_in[4];
    const float* pe_w   = (const float*)d_in[5];
    const float* pe_b   = (const float*)d_in[6];
    const float* edge_w = (const float*)d_in[7];
    const float* ne_g   = (const float*)d_in[8];
    const float* ne_b   = (const float*)d_in[9];
    const float* node_w = (const float*)d_in[10];
    const float* nn_g   = (const float*)d_in[11];
    const float* nn_b   = (const float*)d_in[12];
    float* out = (float*)d_out;

    unsigned short* wt = (unsigned short*)d_ws;

    wprep_kernel<<<(EDGE_IN_*EF_ + 255)/256, 256, 0, stream>>>(edge_w, wt);
    v_kernel<<<B_*L_, 128, 0, stream>>>(memb, node_w, nn_g, nn_b, out);
    fused_kernel<<<B_*L_, 256, 0, stream>>>(X, mask, Ridx, chains, pe_w, pe_b,
                                            wt, ne_g, ne_b, out);
}

// Round 15
// 88.829 us; speedup vs baseline: 1.0563x; 1.0250x over previous
//
#include <hip/hip_runtime.h>
#include <math.h>

#define B_ 4
#define L_ 1024
#define K_ 48
#define EF_ 128
#define NF_ 128
#define NPE_ 16
#define NRBF_ 16
#define MAXREL_ 32
#define EDGE_IN_ 416   // NPE + NRBF*25

#define V_SIZE   (B_*L_*NF_)          // 524288
#define E_OFF    (V_SIZE)
#define E_SIZE   (B_*L_*K_*EF_)       // 25165824
#define EIDX_OFF (E_OFF + E_SIZE)     // 25690112

#define XH_STRIDE 232                 // bf16 per half-row (224 + 8 pad), 464 B

typedef __attribute__((ext_vector_type(8))) short bf16x8;
typedef __attribute__((ext_vector_type(4))) float f32x4;
typedef __attribute__((ext_vector_type(4))) unsigned u32x4;

// atom order: N=0, Ca=1, C=2, O=3, Cb=4. Group 0 = (Ca,Ca), then the 24 PAIRS.
__device__ const int PA_[25] = {1, 0,2,3,4, 1,1,1,1, 0,0,0, 4,4, 3, 0,2,3,4, 2,3,4, 2,3, 2};
__device__ const int PB_[25] = {1, 0,2,3,4, 0,2,3,4, 2,3,4, 2,3, 2, 1,1,1,1, 0,0,0, 4,4, 3};

__device__ __forceinline__ unsigned short f2bf(float f){   // RNE float->bf16
    unsigned u = __float_as_uint(f);
    unsigned r = u + 0x7fffu + ((u >> 16) & 1u);
    return (unsigned short)(r >> 16);
}

__device__ __forceinline__ float pair_dist(const float* sAI, const float (*sAJ)[16], int e, int g2) {
    float dx = sAI[PA_[g2]*3+0] - sAJ[e][PB_[g2]*3+0];
    float dy = sAI[PA_[g2]*3+1] - sAJ[e][PB_[g2]*3+1];
    float dz = sAI[PA_[g2]*3+2] - sAJ[e][PB_[g2]*3+2];
    return sqrtf(dx*dx + dy*dy + dz*dz + 1e-6f);
}

// 16 RBFs via 2-exp recurrence: f(t-D) = f(t)*m, m' = m*exp(-2D^2).
// dist clamped to 28 so m0 = exp(2*D*t0 - D^2) stays finite (<=exp(43.2));
// for d>28 both true and clamped RBF values are < 2e-9 (≈0 at bf16).
__device__ __forceinline__ void rbf16(unsigned short* dst, float dist) {
    float d = fminf(dist, 28.0f);
    float t = 0.8f * d - 1.6f;
    const float DT = 1.06666672f;
    float e = __expf(-t * t);
    float m = __expf(2.0f * DT * t - DT * DT);
    const float c = 0.1027390f;      // exp(-2*DT*DT)
    unsigned pk[8];
    #pragma unroll
    for (int rr = 0; rr < 8; ++rr) {
        float v0 = e;  e *= m;  m *= c;
        float v1 = e;  e *= m;  m *= c;
        asm("v_cvt_pk_bf16_f32 %0, %1, %2" : "=v"(pk[rr]) : "v"(v0), "v"(v1));
    }
    u32x4 w0 = {pk[0], pk[1], pk[2], pk[3]};
    u32x4 w1 = {pk[4], pk[5], pk[6], pk[7]};
    *(u32x4*)dst = w0;
    *(u32x4*)(dst + 8) = w1;
}

template<int NKS, int KB>
__device__ __forceinline__ void mfma_half(f32x4 (&acc)[3][2], const unsigned short* xh,
                                          const unsigned short* w0p, const unsigned short* w1p,
                                          int lr, int lg) {
    #pragma unroll
    for (int ks = 0; ks < NKS; ++ks) {
        int k0 = ks * 32;
        bf16x8 a0, a1, a2, wb0, wb1;
        wb0 = *(const bf16x8*)(w0p + KB + k0);
        wb1 = *(const bf16x8*)(w1p + KB + k0);
        a0 = *(const bf16x8*)&xh[(lr)      * XH_STRIDE + k0 + lg*8];
        a1 = *(const bf16x8*)&xh[(16 + lr) * XH_STRIDE + k0 + lg*8];
        a2 = *(const bf16x8*)&xh[(32 + lr) * XH_STRIDE + k0 + lg*8];
        acc[0][0] = __builtin_amdgcn_mfma_f32_16x16x32_bf16(a0, wb0, acc[0][0], 0, 0, 0);
        acc[0][1] = __builtin_amdgcn_mfma_f32_16x16x32_bf16(a0, wb1, acc[0][1], 0, 0, 0);
        acc[1][0] = __builtin_amdgcn_mfma_f32_16x16x32_bf16(a1, wb0, acc[1][0], 0, 0, 0);
        acc[1][1] = __builtin_amdgcn_mfma_f32_16x16x32_bf16(a1, wb1, acc[1][1], 0, 0, 0);
        acc[2][0] = __builtin_amdgcn_mfma_f32_16x16x32_bf16(a2, wb0, acc[2][0], 0, 0, 0);
        acc[2][1] = __builtin_amdgcn_mfma_f32_16x16x32_bf16(a2, wb1, acc[2][1], 0, 0, 0);
    }
}

// ---------------- weight prep: fp32 [416][128] -> bf16 transposed [128][416] ----------------
__global__ __launch_bounds__(256) void wprep_kernel(const float* __restrict__ w,
                                                    unsigned short* __restrict__ wt)
{
    int idx = blockIdx.x * 256 + threadIdx.x;
    if (idx >= EDGE_IN_ * EF_) return;
    int f = idx & 127;
    int k = idx >> 7;
    wt[f * EDGE_IN_ + k] = f2bf(w[k * EF_ + f]);
}

// ---------------- V = LN(node_w[label]) ----------------
__global__ __launch_bounds__(128) void v_kernel(const int* __restrict__ labels,
                                                const float* __restrict__ node_w,
                                                const float* __restrict__ g,
                                                const float* __restrict__ bb,
                                                float* __restrict__ out)
{
    int gi = blockIdx.x;
    int f  = threadIdx.x;
    int lbl = labels[gi];
    float v = node_w[lbl*NF_ + f];

    __shared__ float red[2];
    __shared__ float red2[2];
    float s = v;
    #pragma unroll
    for (int m = 1; m < 64; m <<= 1) s += __shfl_xor(s, m, 64);
    if ((f & 63) == 0) red[f >> 6] = s;
    __syncthreads();
    float mu = (red[0] + red[1]) * (1.0f / NF_);
    float d = v - mu;
    float s2 = d * d;
    #pragma unroll
    for (int m = 1; m < 64; m <<= 1) s2 += __shfl_xor(s2, m, 64);
    if ((f & 63) == 0) red2[f >> 6] = s2;
    __syncthreads();
    float var = (red2[0] + red2[1]) * (1.0f / NF_);
    out[gi*NF_ + f] = d * rsqrtf(var + 1e-5f) * g[f] + bb[f];
}

// ---------------- fused: top-K select + edge features + MFMA + LN ----------------
// Phase 1: 4096-bin single-pass radix-select (exact; byte-radix fallback if bin>64).
// Phase 2: half-K staged features + MFMA; LN from accumulators via stats LDS.
// LDS alias plan (sBuf 22272 B):
//   phase1: sCa[0..12288) sM[12288..16384) -> hist32[0..16384) cand@16384
//   phase2: xh[0..22272) -> (after last MFMA + barrier) stats@16384 stats2@17152
__global__ __launch_bounds__(256, 6) void fused_kernel(const float* __restrict__ X,
                                                   const float* __restrict__ mask,
                                                   const int* __restrict__ Ridx,
                                                   const int* __restrict__ chains,
                                                   const float* __restrict__ pe_w,
                                                   const float* __restrict__ pe_b,
                                                   const unsigned short* __restrict__ wt,
                                                   const float* __restrict__ ne_g,
                                                   const float* __restrict__ ne_b,
                                                   float* __restrict__ out)
{
    __shared__ __align__(16) unsigned char sBuf[K_ * XH_STRIDE * 2];
    __shared__ float sAI[16];
    __shared__ float sAJ[K_][16];
    __shared__ int   sJ[K_];
    __shared__ int   sDpos[K_];
    __shared__ float wmax[4];
    __shared__ unsigned wsum[4];
    __shared__ int sSelBin;
    __shared__ unsigned sSelLo, sSelCnt, sCnt, sCnt2;
    __shared__ unsigned long long sTkey;

    float* sCa = (float*)sBuf;
    float* sM  = (float*)(sBuf + 12288);
    unsigned* hist32 = (unsigned*)sBuf;
    unsigned short* xh = (unsigned short*)sBuf;
    unsigned long long* cand = (unsigned long long*)(sBuf + 16384);  // phase-1 tail
    float* stats  = (float*)(sBuf + 16384);                          // post-MFMA alias
    float* stats2 = (float*)(sBuf + 17152);

    int tid = threadIdx.x;
    int gi  = blockIdx.x;
    int b   = gi >> 10;
    int i   = gi & (L_ - 1);

    // ================= phase 1: top-K =================
    for (int j = tid; j < L_; j += 256) {
        const float* xr = X + ((size_t)((b << 10) + j)) * 12 + 3;   // Ca
        sCa[j*3+0] = xr[0];
        sCa[j*3+1] = xr[1];
        sCa[j*3+2] = xr[2];
        sM[j] = mask[(b << 10) + j];
    }
    if (tid == 0) { sCnt = 0; sCnt2 = 0; }
    __syncthreads();

    float cx = sCa[i*3+0], cy = sCa[i*3+1], cz = sCa[i*3+2];
    float mi = sM[i];

    // one distance pass; dist/m2 stay in registers
    float dist4[4], m2r[4];
    float lmax = 0.0f;
    #pragma unroll
    for (int q = 0; q < 4; ++q) {
        int j = tid + q * 256;
        float dx = cx - sCa[j*3+0];
        float dy = cy - sCa[j*3+1];
        float dz = cz - sCa[j*3+2];
        float dist = sqrtf(dx*dx + dy*dy + dz*dz + 1e-6f);
        float m2 = mi * sM[j];
        dist4[q] = dist; m2r[q] = m2;
        lmax = fmaxf(lmax, m2 * dist);
    }
    #pragma unroll
    for (int m = 1; m < 64; m <<= 1) lmax = fmaxf(lmax, __shfl_xor(lmax, m, 64));
    if ((tid & 63) == 0) wmax[tid >> 6] = lmax;
    __syncthreads();          // sCa/sM dead after this point
    float Dmax = fmaxf(fmaxf(wmax[0], wmax[1]), fmaxf(wmax[2], wmax[3]));

    unsigned long long key[4];
    #pragma unroll
    for (int q = 0; q < 4; ++q) {
        int j = tid + q * 256;
        float Dadj = m2r[q] * dist4[q] + (1.0f - m2r[q]) * Dmax;
        key[q] = (((unsigned long long)__float_as_uint(Dadj)) << 32) | (unsigned)j;
    }

    // ---- 4096-bin histogram over Dadj bits [30:19] (key bits [62:51]) ----
    for (int k = tid; k < 4096; k += 256) hist32[k] = 0;
    __syncthreads();
    #pragma unroll
    for (int q = 0; q < 4; ++q)
        atomicAdd(&hist32[(unsigned)(key[q] >> 51) & 0xFFFu], 1u);
    __syncthreads();

    // scan: thread t owns bins [16t, 16t+16)
    u32x4 h4[4];
    #pragma unroll
    for (int k = 0; k < 4; ++k) h4[k] = *(u32x4*)&hist32[tid*16 + k*4];
    unsigned loc[16], tot = 0;
    #pragma unroll
    for (int k = 0; k < 16; ++k) { tot += h4[k>>2][k&3]; loc[k] = tot; }
    unsigned ws = tot;
    #pragma unroll
    for (int m = 1; m < 64; m <<= 1) {
        unsigned o = __shfl_up(ws, m, 64);
        if ((tid & 63) >= m) ws += o;
    }
    if ((tid & 63) == 63) wsum[tid >> 6] = ws;
    __syncthreads();
    unsigned base = ws - tot;
    for (int w = 0; w < (tid >> 6); ++w) base += wsum[w];
    unsigned lo_t = base;
    #pragma unroll
    for (int k = 0; k < 16; ++k) {
        unsigned hi_t = base + loc[k];
        if (47u >= lo_t && 47u < hi_t) { sSelBin = tid*16 + k; sSelLo = lo_t; sSelCnt = hi_t - lo_t; }
        lo_t = hi_t;
    }
    __syncthreads();
    unsigned bsel = (unsigned)sSelBin, lo = sSelLo, c = sSelCnt;
    unsigned long long T;

    if (c == 1) {
        #pragma unroll
        for (int q = 0; q < 4; ++q)
            if (((unsigned)(key[q] >> 51) & 0xFFFu) == bsel) sTkey = key[q];
        __syncthreads();
        T = sTkey;
    } else if (c <= 64) {
        #pragma unroll
        for (int q = 0; q < 4; ++q)
            if (((unsigned)(key[q] >> 51) & 0xFFFu) == bsel) {
                unsigned pos = atomicAdd(&sCnt, 1u);
                cand[pos] = key[q];
            }
        __syncthreads();
        if (tid < 64) {
            unsigned long long k64 = (tid < (int)c) ? cand[tid] : 0xffffffffffffffffULL;
            #pragma unroll
            for (unsigned kk = 2; kk <= 64; kk <<= 1) {
                #pragma unroll
                for (unsigned jj = kk >> 1; jj > 0; jj >>= 1) {
                    unsigned long long o = __shfl_xor(k64, jj, 64);
                    bool lower = (tid & jj) == 0;
                    bool asc   = (tid & kk) == 0;
                    unsigned long long mn = (k64 < o) ? k64 : o;
                    unsigned long long mx = (k64 < o) ? o : k64;
                    k64 = (lower == asc) ? mn : mx;
                }
            }
            if (tid == (int)(47u - lo)) sTkey = k64;   // exact rank-47 key
        }
        __syncthreads();
        T = sTkey;
    } else {
        // cold fallback: original exact 6-pass byte radix (256 bins reuse hist32)
        bool act[4] = {true, true, true, true};
        unsigned r = K_ - 1;
        T = 0;
        const int shifts[6] = {56, 48, 40, 32, 8, 0};
        #pragma unroll 1
        for (int p = 0; p < 6; ++p) {
            int sh = shifts[p];
            hist32[tid] = 0;
            __syncthreads();
            #pragma unroll
            for (int q = 0; q < 4; ++q)
                if (act[q]) atomicAdd(&hist32[(unsigned)((key[q] >> sh) & 255ULL)], 1u);
            __syncthreads();
            if (tid < 64) {
                unsigned b0 = hist32[tid*4+0], b1 = hist32[tid*4+1], b2 = hist32[tid*4+2], b3 = hist32[tid*4+3];
                unsigned s0 = b0, s1 = s0 + b1, s2 = s1 + b2, s3 = s2 + b3;
                unsigned s = s3;
                #pragma unroll
                for (int m = 1; m < 64; m <<= 1) {
                    unsigned o = __shfl_up(s, m, 64);
                    if (tid >= m) s += o;
                }
                unsigned bse = s - s3;
                hist32[tid*4+0] = bse + s0;
                hist32[tid*4+1] = bse + s1;
                hist32[tid*4+2] = bse + s2;
                hist32[tid*4+3] = bse + s3;
            }
            __syncthreads();
            unsigned lo2 = (tid == 0) ? 0u : hist32[tid - 1];
            unsigned hi2 = hist32[tid];
            if (r >= lo2 && r < hi2) { sSelBin = tid; sSelLo = lo2; }
            __syncthreads();
            int bs2 = sSelBin;
            r -= sSelLo;
            T |= ((unsigned long long)(unsigned)bs2) << sh;
            #pragma unroll
            for (int q = 0; q < 4; ++q)
                act[q] = act[q] && ((unsigned)((key[q] >> sh) & 255ULL) == (unsigned)bs2);
            __syncthreads();
        }
    }

    // exactly 48 keys <= T (keys unique); separate counter (no reset barrier)
    #pragma unroll
    for (int q = 0; q < 4; ++q)
        if (key[q] <= T) {
            unsigned pos = atomicAdd(&sCnt2, 1u);
            cand[pos] = key[q];
        }
    __syncthreads();

    // wave 0: in-register bitonic sort of 64 (48 real + pad), emit ascending
    if (tid < 64) {
        unsigned long long k64 = (tid < K_) ? cand[tid] : 0xffffffffffffffffULL;
        #pragma unroll
        for (unsigned kk = 2; kk <= 64; kk <<= 1) {
            #pragma unroll
            for (unsigned jj = kk >> 1; jj > 0; jj >>= 1) {
                unsigned long long o = __shfl_xor(k64, jj, 64);
                bool lower = (tid & jj) == 0;
                bool asc   = (tid & kk) == 0;
                unsigned long long mn = (k64 < o) ? k64 : o;
                unsigned long long mx = (k64 < o) ? o : k64;
                k64 = (lower == asc) ? mn : mx;
            }
        }
        if (tid < K_) {
            int j = (int)(unsigned)(k64 & 0xffffffffULL);
            sJ[tid] = j;
            out[EIDX_OFF + (size_t)gi * K_ + tid] = (float)j;
        }
    }
    __syncthreads();

    // ================= phase 2: edge features + MFMA + LN =================
    if (tid < K_ + 1) {
        int rr = (tid < K_) ? sJ[tid] : i;
        const float* xr = X + ((size_t)((b << 10) + rr)) * 12;
        float n0=xr[0],  n1=xr[1],  n2=xr[2];
        float a0=xr[3],  a1=xr[4],  a2=xr[5];
        float c0=xr[6],  c1=xr[7],  c2=xr[8];
        float o0=xr[9],  o1=xr[10], o2=xr[11];
        float bx=a0-n0, by=a1-n1, bz=a2-n2;
        float vx=c0-a0, vy=c1-a1, vz=c2-a2;
        float ax = by*vz - bz*vy;
        float ay = bz*vx - bx*vz;
        float az = bx*vy - by*vx;
        float cb0 = -0.58273431f*ax + 0.56802827f*bx - 0.54067466f*vx + a0;
        float cb1 = -0.58273431f*ay + 0.56802827f*by - 0.54067466f*vy + a1;
        float cb2 = -0.58273431f*az + 0.56802827f*bz - 0.54067466f*vz + a2;
        float* dst = (tid < K_) ? &sAJ[tid][0] : &sAI[0];
        dst[0]=n0;  dst[1]=n1;  dst[2]=n2;
        dst[3]=a0;  dst[4]=a1;  dst[5]=a2;
        dst[6]=c0;  dst[7]=c1;  dst[8]=c2;
        dst[9]=o0;  dst[10]=o1; dst[11]=o2;
        dst[12]=cb0; dst[13]=cb1; dst[14]=cb2;
    }
    if (tid >= 64 && tid < 64 + K_) {
        int e = tid - 64;
        int j = sJ[e];
        int off  = Ridx[gi] - Ridx[(b << 10) + j];
        int same = (chains[gi] == chains[(b << 10) + j]);
        int dcl = off + MAXREL_;
        dcl = dcl < 0 ? 0 : (dcl > 2*MAXREL_ ? 2*MAXREL_ : dcl);
        sDpos[e] = same ? dcl : (2*MAXREL_ + 1);
    }
    __syncthreads();

    const int wv = tid >> 6;
    const int ln = tid & 63;
    const int lr = ln & 15;
    const int lg = ln >> 4;

    f32x4 acc[3][2];
    #pragma unroll
    for (int rf = 0; rf < 3; ++rf)
        #pragma unroll
        for (int cf = 0; cf < 2; ++cf)
            acc[rf][cf] = (f32x4){0.0f, 0.0f, 0.0f, 0.0f};

    const unsigned short* wbase0 = wt + (size_t)(wv*32 + lr) * EDGE_IN_ + lg*8;
    const unsigned short* wbase1 = wt + (size_t)(wv*32 + 16 + lr) * EDGE_IN_ + lg*8;

    // half 0: PE (cols 0..15) + groups 0..12 (cols 16..223); K 0..223 (R12 mapping)
    #pragma unroll
    for (int p = 0; p < 2; ++p) {
        int idx = tid + p * 256;
        if (idx < 384) {
            int e = idx >> 3, cc = (idx & 7) * 2;
            int dp = sDpos[e];
            float v0 = pe_w[dp*NPE_ + cc]     + pe_b[cc];
            float v1 = pe_w[dp*NPE_ + cc + 1] + pe_b[cc + 1];
            unsigned pk;
            asm("v_cvt_pk_bf16_f32 %0, %1, %2" : "=v"(pk) : "v"(v0), "v"(v1));
            *(unsigned*)&xh[e * XH_STRIDE + cc] = pk;
        }
    }
    #pragma unroll
    for (int p = 0; p < 3; ++p) {       // 48 x 13 groups = 624 items
        int idx = tid + p * 256;
        if (idx < 624) {
            int e = idx / 13, g = idx - e * 13;
            rbf16(&xh[e * XH_STRIDE + NPE_ + g * 16], pair_dist(sAI, sAJ, e, g));
        }
    }
    __syncthreads();
    mfma_half<7, 0>(acc, xh, wbase0, wbase1, lr, lg);
    __syncthreads();
    // half 1: groups 13..24 (cols 0..191 local); K 224..415
    #pragma unroll
    for (int p = 0; p < 3; ++p) {       // 48 x 12 groups = 576 items
        int idx = tid + p * 256;
        if (idx < 576) {
            int e = idx / 12, g = 13 + (idx - e * 12);
            rbf16(&xh[e * XH_STRIDE + (g - 13) * 16], pair_dist(sAI, sAJ, e, g));
        }
    }
    __syncthreads();
    mfma_half<6, 224>(acc, xh, wbase0, wbase1, lr, lg);
    __syncthreads();   // xh reads complete before stats alias is written

    // ---- LN from accumulators: per-row stats via lr-group shfl + stats LDS ----
    #pragma unroll
    for (int rf = 0; rf < 3; ++rf)
        #pragma unroll
        for (int r4 = 0; r4 < 4; ++r4) {
            float v0 = acc[rf][0][r4], v1 = acc[rf][1][r4];
            float s  = v0 + v1;
            float s2 = v0*v0 + v1*v1;
            #pragma unroll
            for (int m = 1; m < 16; m <<= 1) {
                s  += __shfl_xor(s,  m, 64);
                s2 += __shfl_xor(s2, m, 64);
            }
            if (lr == 0) {
                int row = rf*16 + lg*4 + r4;
                stats [wv*K_ + row] = s;
                stats2[wv*K_ + row] = s2;
            }
        }
    __syncthreads();

    int colg = wv*32 + lr;
    float gv0 = ne_g[colg],      bv0 = ne_b[colg];
    float gv1 = ne_g[colg + 16], bv1 = ne_b[colg + 16];

    #pragma unroll
    for (int rf = 0; rf < 3; ++rf)
        #pragma unroll
        for (int r4 = 0; r4 < 4; ++r4) {
            int row = rf*16 + lg*4 + r4;
            float sum = stats [row] + stats [K_ + row] + stats [2*K_ + row] + stats [3*K_ + row];
            float sq  = stats2[row] + stats2[K_ + row] + stats2[2*K_ + row] + stats2[3*K_ + row];
            float mu   = sum * (1.0f / 128.0f);
            float var  = sq * (1.0f / 128.0f) - mu * mu;
            float rstd = rsqrtf(var + 1e-5f);
            float* dst = out + E_OFF + (size_t)(gi * K_ + row) * EF_ + colg;
            __builtin_nontemporal_store((acc[rf][0][r4] - mu) * rstd * gv0 + bv0, dst);
            __builtin_nontemporal_store((acc[rf][1][r4] - mu) * rstd * gv1 + bv1, dst + 16);
        }
}

extern "C" void kernel_launch(void* const* d_in, const int* in_sizes, int n_in,
                              void* d_out, int out_size, void* d_ws, size_t ws_size,
                              hipStream_t stream)
{
    const float* X      = (const float*)d_in[0];
    const float* mask   = (const float*)d_in[1];
    const int*   Ridx   = (const int*)d_in[2];
    const int*   chains = (const int*)d_in[3];
    const int*   memb   = (const int*)d_in[4];
    const float* pe_w   = (const float*)d_in[5];
    const float* pe_b   = (const float*)d_in[6];
    const float* edge_w = (const float*)d_in[7];
    const float* ne_g   = (const float*)d_in[8];
    const float* ne_b   = (const float*)d_in[9];
    const float* node_w = (const float*)d_in[10];
    const float* nn_g   = (const float*)d_in[11];
    const float* nn_b   = (const float*)d_in[12];
    float* out = (float*)d_out;

    unsigned short* wt = (unsigned short*)d_ws;

    wprep_kernel<<<(EDGE_IN_*EF_ + 255)/256, 256, 0, stream>>>(edge_w, wt);
    v_kernel<<<B_*L_, 128, 0, stream>>>(memb, node_w, nn_g, nn_b, out);
    fused_kernel<<<B_*L_, 256, 0, stream>>>(X, mask, Ridx, chains, pe_w, pe_b,
                                            wt, ne_g, ne_b, out);
}

// Round 16
// 88.140 us; speedup vs baseline: 1.0646x; 1.0078x over previous
//
#include <hip/hip_runtime.h>
#include <math.h>

#define B_ 4
#define L_ 1024
#define K_ 48
#define EF_ 128
#define NF_ 128
#define NPE_ 16
#define NRBF_ 16
#define MAXREL_ 32
#define EDGE_IN_ 416   // NPE + NRBF*25

#define V_SIZE   (B_*L_*NF_)          // 524288
#define E_OFF    (V_SIZE)
#define E_SIZE   (B_*L_*K_*EF_)       // 25165824
#define EIDX_OFF (E_OFF + E_SIZE)     // 25690112

#define XH_STRIDE 232                 // bf16 per half-row (224 + 8 pad), 464 B

typedef __attribute__((ext_vector_type(8))) short bf16x8;
typedef __attribute__((ext_vector_type(4))) float f32x4;
typedef __attribute__((ext_vector_type(4))) unsigned u32x4;

// atom order: N=0, Ca=1, C=2, O=3, Cb=4. Group 0 = (Ca,Ca), then the 24 PAIRS.
__device__ const int PA_[25] = {1, 0,2,3,4, 1,1,1,1, 0,0,0, 4,4, 3, 0,2,3,4, 2,3,4, 2,3, 2};
__device__ const int PB_[25] = {1, 0,2,3,4, 0,2,3,4, 2,3,4, 2,3, 2, 1,1,1,1, 0,0,0, 4,4, 3};

__device__ __forceinline__ unsigned short f2bf(float f){   // RNE float->bf16
    unsigned u = __float_as_uint(f);
    unsigned r = u + 0x7fffu + ((u >> 16) & 1u);
    return (unsigned short)(r >> 16);
}

__device__ __forceinline__ float pair_dist(const float* sAI, const float (*sAJ)[16], int e, int g2) {
    float dx = sAI[PA_[g2]*3+0] - sAJ[e][PB_[g2]*3+0];
    float dy = sAI[PA_[g2]*3+1] - sAJ[e][PB_[g2]*3+1];
    float dz = sAI[PA_[g2]*3+2] - sAJ[e][PB_[g2]*3+2];
    return sqrtf(dx*dx + dy*dy + dz*dz + 1e-6f);
}

// direct 16-exp RBF (proven absmax 0.031; R15's recurrence was perf-flat and
// cost 50x error margin -> reverted)
__device__ __forceinline__ void rbf16(unsigned short* dst, float dist) {
    float t = 0.8f * dist - 1.6f;
    unsigned pk[8];
    #pragma unroll
    for (int rr = 0; rr < 8; ++rr) {
        float v0 = __expf(-t * t); t -= 1.06666672f;
        float v1 = __expf(-t * t); t -= 1.06666672f;
        asm("v_cvt_pk_bf16_f32 %0, %1, %2" : "=v"(pk[rr]) : "v"(v0), "v"(v1));
    }
    u32x4 w0 = {pk[0], pk[1], pk[2], pk[3]};
    u32x4 w1 = {pk[4], pk[5], pk[6], pk[7]};
    *(u32x4*)dst = w0;
    *(u32x4*)(dst + 8) = w1;
}

template<int NKS, int KB>
__device__ __forceinline__ void mfma_half(f32x4 (&acc)[3][2], const unsigned short* xh,
                                          const unsigned short* w0p, const unsigned short* w1p,
                                          int lr, int lg) {
    #pragma unroll
    for (int ks = 0; ks < NKS; ++ks) {
        int k0 = ks * 32;
        bf16x8 a0, a1, a2, wb0, wb1;
        wb0 = *(const bf16x8*)(w0p + KB + k0);
        wb1 = *(const bf16x8*)(w1p + KB + k0);
        a0 = *(const bf16x8*)&xh[(lr)      * XH_STRIDE + k0 + lg*8];
        a1 = *(const bf16x8*)&xh[(16 + lr) * XH_STRIDE + k0 + lg*8];
        a2 = *(const bf16x8*)&xh[(32 + lr) * XH_STRIDE + k0 + lg*8];
        acc[0][0] = __builtin_amdgcn_mfma_f32_16x16x32_bf16(a0, wb0, acc[0][0], 0, 0, 0);
        acc[0][1] = __builtin_amdgcn_mfma_f32_16x16x32_bf16(a0, wb1, acc[0][1], 0, 0, 0);
        acc[1][0] = __builtin_amdgcn_mfma_f32_16x16x32_bf16(a1, wb0, acc[1][0], 0, 0, 0);
        acc[1][1] = __builtin_amdgcn_mfma_f32_16x16x32_bf16(a1, wb1, acc[1][1], 0, 0, 0);
        acc[2][0] = __builtin_amdgcn_mfma_f32_16x16x32_bf16(a2, wb0, acc[2][0], 0, 0, 0);
        acc[2][1] = __builtin_amdgcn_mfma_f32_16x16x32_bf16(a2, wb1, acc[2][1], 0, 0, 0);
    }
}

// ---------------- weight prep: fp32 [416][128] -> bf16 transposed [128][416] ----------------
__global__ __launch_bounds__(256) void wprep_kernel(const float* __restrict__ w,
                                                    unsigned short* __restrict__ wt)
{
    int idx = blockIdx.x * 256 + threadIdx.x;
    if (idx >= EDGE_IN_ * EF_) return;
    int f = idx & 127;
    int k = idx >> 7;
    wt[f * EDGE_IN_ + k] = f2bf(w[k * EF_ + f]);
}

// ---------------- V = LN(node_w[label]) ----------------
__global__ __launch_bounds__(128) void v_kernel(const int* __restrict__ labels,
                                                const float* __restrict__ node_w,
                                                const float* __restrict__ g,
                                                const float* __restrict__ bb,
                                                float* __restrict__ out)
{
    int gi = blockIdx.x;
    int f  = threadIdx.x;
    int lbl = labels[gi];
    float v = node_w[lbl*NF_ + f];

    __shared__ float red[2];
    __shared__ float red2[2];
    float s = v;
    #pragma unroll
    for (int m = 1; m < 64; m <<= 1) s += __shfl_xor(s, m, 64);
    if ((f & 63) == 0) red[f >> 6] = s;
    __syncthreads();
    float mu = (red[0] + red[1]) * (1.0f / NF_);
    float d = v - mu;
    float s2 = d * d;
    #pragma unroll
    for (int m = 1; m < 64; m <<= 1) s2 += __shfl_xor(s2, m, 64);
    if ((f & 63) == 0) red2[f >> 6] = s2;
    __syncthreads();
    float var = (red2[0] + red2[1]) * (1.0f / NF_);
    out[gi*NF_ + f] = d * rsqrtf(var + 1e-5f) * g[f] + bb[f];
}

// ---------------- fused: top-K select + edge features + MFMA + LN ----------------
// Phase 1: direct-global distance pass (no LDS staging; X is L2-resident) +
//          4096-bin single-pass radix-select (exact; byte-radix fallback if bin>64).
// Phase 2: half-K staged features + MFMA; LN from accumulators via stats LDS.
// LDS alias plan (sBuf 22272 B):
//   phase1: hist32[0..16384) cand@16384
//   phase2: xh[0..22272) -> (after last MFMA + barrier) stats@16384 stats2@17152
__global__ __launch_bounds__(256, 6) void fused_kernel(const float* __restrict__ X,
                                                   const float* __restrict__ mask,
                                                   const int* __restrict__ Ridx,
                                                   const int* __restrict__ chains,
                                                   const float* __restrict__ pe_w,
                                                   const float* __restrict__ pe_b,
                                                   const unsigned short* __restrict__ wt,
                                                   const float* __restrict__ ne_g,
                                                   const float* __restrict__ ne_b,
                                                   float* __restrict__ out)
{
    __shared__ __align__(16) unsigned char sBuf[K_ * XH_STRIDE * 2];
    __shared__ float sAI[16];
    __shared__ float sAJ[K_][16];
    __shared__ int   sJ[K_];
    __shared__ int   sDpos[K_];
    __shared__ float wmax[4];
    __shared__ unsigned wsum[4];
    __shared__ int sSelBin;
    __shared__ unsigned sSelLo, sSelCnt, sCnt, sCnt2;
    __shared__ unsigned long long sTkey;

    unsigned* hist32 = (unsigned*)sBuf;
    unsigned short* xh = (unsigned short*)sBuf;
    unsigned long long* cand = (unsigned long long*)(sBuf + 16384);  // phase-1 tail
    float* stats  = (float*)(sBuf + 16384);                          // post-MFMA alias
    float* stats2 = (float*)(sBuf + 17152);

    int tid = threadIdx.x;
    int gi  = blockIdx.x;
    int b   = gi >> 10;
    int i   = gi & (L_ - 1);

    // ================= phase 1: top-K (no staging; direct L2-resident loads) =================
    const float* Xb = X + ((size_t)(b << 10)) * 12;
    const float* mb = mask + (b << 10);
    float cx, cy, cz, mi;
    {
        const float* xi = Xb + (size_t)i * 12 + 3;   // Ca of residue i (L1-broadcast)
        cx = xi[0]; cy = xi[1]; cz = xi[2];
        mi = mb[i];
    }
    if (tid == 0) { sCnt = 0; sCnt2 = 0; }

    // one distance pass; dist/m2 stay in registers
    float dist4[4], m2r[4];
    float lmax = 0.0f;
    #pragma unroll
    for (int q = 0; q < 4; ++q) {
        int j = tid + q * 256;
        const float* xj = Xb + (size_t)j * 12 + 3;
        float dx = cx - xj[0];
        float dy = cy - xj[1];
        float dz = cz - xj[2];
        float dist = sqrtf(dx*dx + dy*dy + dz*dz + 1e-6f);
        float m2 = mi * mb[j];
        dist4[q] = dist; m2r[q] = m2;
        lmax = fmaxf(lmax, m2 * dist);
    }
    #pragma unroll
    for (int m = 1; m < 64; m <<= 1) lmax = fmaxf(lmax, __shfl_xor(lmax, m, 64));
    if ((tid & 63) == 0) wmax[tid >> 6] = lmax;
    __syncthreads();
    float Dmax = fmaxf(fmaxf(wmax[0], wmax[1]), fmaxf(wmax[2], wmax[3]));

    unsigned long long key[4];
    #pragma unroll
    for (int q = 0; q < 4; ++q) {
        int j = tid + q * 256;
        float Dadj = m2r[q] * dist4[q] + (1.0f - m2r[q]) * Dmax;
        key[q] = (((unsigned long long)__float_as_uint(Dadj)) << 32) | (unsigned)j;
    }

    // ---- 4096-bin histogram over Dadj bits [30:19] (key bits [62:51]) ----
    for (int k = tid; k < 4096; k += 256) hist32[k] = 0;
    __syncthreads();
    #pragma unroll
    for (int q = 0; q < 4; ++q)
        atomicAdd(&hist32[(unsigned)(key[q] >> 51) & 0xFFFu], 1u);
    __syncthreads();

    // scan: thread t owns bins [16t, 16t+16)
    u32x4 h4[4];
    #pragma unroll
    for (int k = 0; k < 4; ++k) h4[k] = *(u32x4*)&hist32[tid*16 + k*4];
    unsigned loc[16], tot = 0;
    #pragma unroll
    for (int k = 0; k < 16; ++k) { tot += h4[k>>2][k&3]; loc[k] = tot; }
    unsigned ws = tot;
    #pragma unroll
    for (int m = 1; m < 64; m <<= 1) {
        unsigned o = __shfl_up(ws, m, 64);
        if ((tid & 63) >= m) ws += o;
    }
    if ((tid & 63) == 63) wsum[tid >> 6] = ws;
    __syncthreads();
    unsigned base = ws - tot;
    for (int w = 0; w < (tid >> 6); ++w) base += wsum[w];
    unsigned lo_t = base;
    #pragma unroll
    for (int k = 0; k < 16; ++k) {
        unsigned hi_t = base + loc[k];
        if (47u >= lo_t && 47u < hi_t) { sSelBin = tid*16 + k; sSelLo = lo_t; sSelCnt = hi_t - lo_t; }
        lo_t = hi_t;
    }
    __syncthreads();
    unsigned bsel = (unsigned)sSelBin, lo = sSelLo, c = sSelCnt;
    unsigned long long T;

    if (c == 1) {
        #pragma unroll
        for (int q = 0; q < 4; ++q)
            if (((unsigned)(key[q] >> 51) & 0xFFFu) == bsel) sTkey = key[q];
        __syncthreads();
        T = sTkey;
    } else if (c <= 64) {
        #pragma unroll
        for (int q = 0; q < 4; ++q)
            if (((unsigned)(key[q] >> 51) & 0xFFFu) == bsel) {
                unsigned pos = atomicAdd(&sCnt, 1u);
                cand[pos] = key[q];
            }
        __syncthreads();
        if (tid < 64) {
            unsigned long long k64 = (tid < (int)c) ? cand[tid] : 0xffffffffffffffffULL;
            #pragma unroll
            for (unsigned kk = 2; kk <= 64; kk <<= 1) {
                #pragma unroll
                for (unsigned jj = kk >> 1; jj > 0; jj >>= 1) {
                    unsigned long long o = __shfl_xor(k64, jj, 64);
                    bool lower = (tid & jj) == 0;
                    bool asc   = (tid & kk) == 0;
                    unsigned long long mn = (k64 < o) ? k64 : o;
                    unsigned long long mx = (k64 < o) ? o : k64;
                    k64 = (lower == asc) ? mn : mx;
                }
            }
            if (tid == (int)(47u - lo)) sTkey = k64;   // exact rank-47 key
        }
        __syncthreads();
        T = sTkey;
    } else {
        // cold fallback: original exact 6-pass byte radix (256 bins reuse hist32)
        bool act[4] = {true, true, true, true};
        unsigned r = K_ - 1;
        T = 0;
        const int shifts[6] = {56, 48, 40, 32, 8, 0};
        #pragma unroll 1
        for (int p = 0; p < 6; ++p) {
            int sh = shifts[p];
            hist32[tid] = 0;
            __syncthreads();
            #pragma unroll
            for (int q = 0; q < 4; ++q)
                if (act[q]) atomicAdd(&hist32[(unsigned)((key[q] >> sh) & 255ULL)], 1u);
            __syncthreads();
            if (tid < 64) {
                unsigned b0 = hist32[tid*4+0], b1 = hist32[tid*4+1], b2 = hist32[tid*4+2], b3 = hist32[tid*4+3];
                unsigned s0 = b0, s1 = s0 + b1, s2 = s1 + b2, s3 = s2 + b3;
                unsigned s = s3;
                #pragma unroll
                for (int m = 1; m < 64; m <<= 1) {
                    unsigned o = __shfl_up(s, m, 64);
                    if (tid >= m) s += o;
                }
                unsigned bse = s - s3;
                hist32[tid*4+0] = bse + s0;
                hist32[tid*4+1] = bse + s1;
                hist32[tid*4+2] = bse + s2;
                hist32[tid*4+3] = bse + s3;
            }
            __syncthreads();
            unsigned lo2 = (tid == 0) ? 0u : hist32[tid - 1];
            unsigned hi2 = hist32[tid];
            if (r >= lo2 && r < hi2) { sSelBin = tid; sSelLo = lo2; }
            __syncthreads();
            int bs2 = sSelBin;
            r -= sSelLo;
            T |= ((unsigned long long)(unsigned)bs2) << sh;
            #pragma unroll
            for (int q = 0; q < 4; ++q)
                act[q] = act[q] && ((unsigned)((key[q] >> sh) & 255ULL) == (unsigned)bs2);
            __syncthreads();
        }
    }

    // exactly 48 keys <= T (keys unique); separate counter (no reset barrier)
    #pragma unroll
    for (int q = 0; q < 4; ++q)
        if (key[q] <= T) {
            unsigned pos = atomicAdd(&sCnt2, 1u);
            cand[pos] = key[q];
        }
    __syncthreads();

    // wave 0: in-register bitonic sort of 64 (48 real + pad), emit ascending
    if (tid < 64) {
        unsigned long long k64 = (tid < K_) ? cand[tid] : 0xffffffffffffffffULL;
        #pragma unroll
        for (unsigned kk = 2; kk <= 64; kk <<= 1) {
            #pragma unroll
            for (unsigned jj = kk >> 1; jj > 0; jj >>= 1) {
                unsigned long long o = __shfl_xor(k64, jj, 64);
                bool lower = (tid & jj) == 0;
                bool asc   = (tid & kk) == 0;
                unsigned long long mn = (k64 < o) ? k64 : o;
                unsigned long long mx = (k64 < o) ? o : k64;
                k64 = (lower == asc) ? mn : mx;
            }
        }
        if (tid < K_) {
            int j = (int)(unsigned)(k64 & 0xffffffffULL);
            sJ[tid] = j;
            out[EIDX_OFF + (size_t)gi * K_ + tid] = (float)j;
        }
    }
    __syncthreads();

    // ================= phase 2: edge features + MFMA + LN =================
    if (tid < K_ + 1) {
        int rr = (tid < K_) ? sJ[tid] : i;
        const float* xr = X + ((size_t)((b << 10) + rr)) * 12;
        float n0=xr[0],  n1=xr[1],  n2=xr[2];
        float a0=xr[3],  a1=xr[4],  a2=xr[5];
        float c0=xr[6],  c1=xr[7],  c2=xr[8];
        float o0=xr[9],  o1=xr[10], o2=xr[11];
        float bx=a0-n0, by=a1-n1, bz=a2-n2;
        float vx=c0-a0, vy=c1-a1, vz=c2-a2;
        float ax = by*vz - bz*vy;
        float ay = bz*vx - bx*vz;
        float az = bx*vy - by*vx;
        float cb0 = -0.58273431f*ax + 0.56802827f*bx - 0.54067466f*vx + a0;
        float cb1 = -0.58273431f*ay + 0.56802827f*by - 0.54067466f*vy + a1;
        float cb2 = -0.58273431f*az + 0.56802827f*bz - 0.54067466f*vz + a2;
        float* dst = (tid < K_) ? &sAJ[tid][0] : &sAI[0];
        dst[0]=n0;  dst[1]=n1;  dst[2]=n2;
        dst[3]=a0;  dst[4]=a1;  dst[5]=a2;
        dst[6]=c0;  dst[7]=c1;  dst[8]=c2;
        dst[9]=o0;  dst[10]=o1; dst[11]=o2;
        dst[12]=cb0; dst[13]=cb1; dst[14]=cb2;
    }
    if (tid >= 64 && tid < 64 + K_) {
        int e = tid - 64;
        int j = sJ[e];
        int off  = Ridx[gi] - Ridx[(b << 10) + j];
        int same = (chains[gi] == chains[(b << 10) + j]);
        int dcl = off + MAXREL_;
        dcl = dcl < 0 ? 0 : (dcl > 2*MAXREL_ ? 2*MAXREL_ : dcl);
        sDpos[e] = same ? dcl : (2*MAXREL_ + 1);
    }
    __syncthreads();

    const int wv = tid >> 6;
    const int ln = tid & 63;
    const int lr = ln & 15;
    const int lg = ln >> 4;

    f32x4 acc[3][2];
    #pragma unroll
    for (int rf = 0; rf < 3; ++rf)
        #pragma unroll
        for (int cf = 0; cf < 2; ++cf)
            acc[rf][cf] = (f32x4){0.0f, 0.0f, 0.0f, 0.0f};

    const unsigned short* wbase0 = wt + (size_t)(wv*32 + lr) * EDGE_IN_ + lg*8;
    const unsigned short* wbase1 = wt + (size_t)(wv*32 + 16 + lr) * EDGE_IN_ + lg*8;

    // half 0: PE (cols 0..15) + groups 0..12 (cols 16..223); K 0..223 (R12 mapping)
    #pragma unroll
    for (int p = 0; p < 2; ++p) {
        int idx = tid + p * 256;
        if (idx < 384) {
            int e = idx >> 3, cc = (idx & 7) * 2;
            int dp = sDpos[e];
            float v0 = pe_w[dp*NPE_ + cc]     + pe_b[cc];
            float v1 = pe_w[dp*NPE_ + cc + 1] + pe_b[cc + 1];
            unsigned pk;
            asm("v_cvt_pk_bf16_f32 %0, %1, %2" : "=v"(pk) : "v"(v0), "v"(v1));
            *(unsigned*)&xh[e * XH_STRIDE + cc] = pk;
        }
    }
    #pragma unroll
    for (int p = 0; p < 3; ++p) {       // 48 x 13 groups = 624 items
        int idx = tid + p * 256;
        if (idx < 624) {
            int e = idx / 13, g = idx - e * 13;
            rbf16(&xh[e * XH_STRIDE + NPE_ + g * 16], pair_dist(sAI, sAJ, e, g));
        }
    }
    __syncthreads();
    mfma_half<7, 0>(acc, xh, wbase0, wbase1, lr, lg);
    __syncthreads();
    // half 1: groups 13..24 (cols 0..191 local); K 224..415
    #pragma unroll
    for (int p = 0; p < 3; ++p) {       // 48 x 12 groups = 576 items
        int idx = tid + p * 256;
        if (idx < 576) {
            int e = idx / 12, g = 13 + (idx - e * 12);
            rbf16(&xh[e * XH_STRIDE + (g - 13) * 16], pair_dist(sAI, sAJ, e, g));
        }
    }
    __syncthreads();
    mfma_half<6, 224>(acc, xh, wbase0, wbase1, lr, lg);
    __syncthreads();   // xh reads complete before stats alias is written

    // ---- LN from accumulators: per-row stats via lr-group shfl + stats LDS ----
    #pragma unroll
    for (int rf = 0; rf < 3; ++rf)
        #pragma unroll
        for (int r4 = 0; r4 < 4; ++r4) {
            float v0 = acc[rf][0][r4], v1 = acc[rf][1][r4];
            float s  = v0 + v1;
            float s2 = v0*v0 + v1*v1;
            #pragma unroll
            for (int m = 1; m < 16; m <<= 1) {
                s  += __shfl_xor(s,  m, 64);
                s2 += __shfl_xor(s2, m, 64);
            }
            if (lr == 0) {
                int row = rf*16 + lg*4 + r4;
                stats [wv*K_ + row] = s;
                stats2[wv*K_ + row] = s2;
            }
        }
    __syncthreads();

    int colg = wv*32 + lr;
    float gv0 = ne_g[colg],      bv0 = ne_b[colg];
    float gv1 = ne_g[colg + 16], bv1 = ne_b[colg + 16];

    #pragma unroll
    for (int rf = 0; rf < 3; ++rf)
        #pragma unroll
        for (int r4 = 0; r4 < 4; ++r4) {
            int row = rf*16 + lg*4 + r4;
            float sum = stats [row] + stats [K_ + row] + stats [2*K_ + row] + stats [3*K_ + row];
            float sq  = stats2[row] + stats2[K_ + row] + stats2[2*K_ + row] + stats2[3*K_ + row];
            float mu   = sum * (1.0f / 128.0f);
            float var  = sq * (1.0f / 128.0f) - mu * mu;
            float rstd = rsqrtf(var + 1e-5f);
            float* dst = out + E_OFF + (size_t)(gi * K_ + row) * EF_ + colg;
            __builtin_nontemporal_store((acc[rf][0][r4] - mu) * rstd * gv0 + bv0, dst);
            __builtin_nontemporal_store((acc[rf][1][r4] - mu) * rstd * gv1 + bv1, dst + 16);
        }
}

extern "C" void kernel_launch(void* const* d_in, const int* in_sizes, int n_in,
                              void* d_out, int out_size, void* d_ws, size_t ws_size,
                              hipStream_t stream)
{
    const float* X      = (const float*)d_in[0];
    const float* mask   = (const float*)d_in[1];
    const int*   Ridx   = (const int*)d_in[2];
    const int*   chains = (const int*)d_in[3];
    const int*   memb   = (const int*)d_in[4];
    const float* pe_w   = (const float*)d_in[5];
    const float* pe_b   = (const float*)d_in[6];
    const float* edge_w = (const float*)d_in[7];
    const float* ne_g   = (const float*)d_in[8];
    const float* ne_b   = (const float*)d_in[9];
    const float* node_w = (const float*)d_in[10];
    const float* nn_g   = (const float*)d_in[11];
    const float* nn_b   = (const float*)d_in[12];
    float* out = (float*)d_out;

    unsigned short* wt = (unsigned short*)d_ws;

    wprep_kernel<<<(EDGE_IN_*EF_ + 255)/256, 256, 0, stream>>>(edge_w, wt);
    v_kernel<<<B_*L_, 128, 0, stream>>>(memb, node_w, nn_g, nn_b, out);
    fused_kernel<<<B_*L_, 256, 0, stream>>>(X, mask, Ridx, chains, pe_w, pe_b,
                                            wt, ne_g, ne_b, out);
}